// Round 4
// baseline (32.897 us; speedup 1.0000x reference)
//
#include <hip/hip_runtime.h>

// NeuralAdditiveModel: out[b] = bias + sum_f ( b2[f] + sum_h relu(x[b,f]*W1[f,h]+b1[f,h]) * W2[f,h] )
// x: [16384, 1024] f32, W1/b1/W2: [1024,16] f32, b2: [1024], bias: [1]. out: [16384] f32.
//
// Mapping: lane owns a FEATURE; 48 params live in VGPRs (small runtime loop body
// keeps them resident); packed fp32 (v_pk_fma/v_pk_max) via <2 x float>;
// 8-row ping-pong x prefetch; shfl pair-reduce -> LDS -> 8-lane reduce -> atomic.

typedef float v2f __attribute__((ext_vector_type(2)));

constexpr int BATCH = 16384;
constexpr int NF    = 1024;
constexpr int HID   = 16;

constexpr int BLOCK = 256;         // 4 waves
constexpr int FG    = 4;           // feature-dim split across blocks
constexpr int FPB   = NF / FG;     // 256 features per block (1 per thread)
constexpr int R     = 32;          // rows per block
constexpr int RB    = BATCH / R;   // 512 row blocks
constexpr int CH    = 8;           // rows per chunk (prefetch depth)
constexpr int NCH   = R / CH;      // 4 chunks
constexpr int CSTR  = 132;         // part[] row stride in dwords (128 cols + 4 pad)

__global__ __launch_bounds__(BLOCK) void nam_init(float* __restrict__ out,
                                                  const float* __restrict__ b2,
                                                  const float* __restrict__ bias) {
    __shared__ float red[BLOCK / 64];
    const int tid = threadIdx.x;
    float s = 0.f;
    #pragma unroll
    for (int k = 0; k < NF / BLOCK; ++k) s += b2[k * BLOCK + tid];
    #pragma unroll
    for (int off = 32; off >= 1; off >>= 1) s += __shfl_xor(s, off, 64);
    if ((tid & 63) == 0) red[tid >> 6] = s;
    __syncthreads();
    const float tot = (red[0] + red[1]) + (red[2] + red[3]);
    out[blockIdx.x * BLOCK + tid] = bias[0] + tot;
}

__global__ __launch_bounds__(BLOCK, 4) void nam_main(const float* __restrict__ x,
                                                     const float* __restrict__ W1,
                                                     const float* __restrict__ b1,
                                                     const float* __restrict__ W2,
                                                     float* __restrict__ out) {
    __shared__ float part[R * CSTR];   // 16896 B

    const int tid  = threadIdx.x;
    const int rb   = blockIdx.x & (RB - 1);   // row block
    const int fg   = blockIdx.x >> 9;         // feature group (blockIdx.x / RB)
    const int row0 = rb * R;
    const int f    = fg * FPB + tid;          // this lane's feature

    // ---- params in VGPRs, packed as float2 pairs (48 regs) ----
    v2f w1[HID / 2], bb[HID / 2], w2[HID / 2];
    #pragma unroll
    for (int i = 0; i < HID / 4; ++i) {
        *reinterpret_cast<float4*>(&w1[2 * i]) =
            *reinterpret_cast<const float4*>(W1 + (size_t)f * HID + 4 * i);
        *reinterpret_cast<float4*>(&bb[2 * i]) =
            *reinterpret_cast<const float4*>(b1 + (size_t)f * HID + 4 * i);
        *reinterpret_cast<float4*>(&w2[2 * i]) =
            *reinterpret_cast<const float4*>(W2 + (size_t)f * HID + 4 * i);
    }

    const float* __restrict__ xp = x + (size_t)row0 * NF + f;

    auto compute8 = [&](const float (&xv)[CH], int rbase) {
        #pragma unroll
        for (int r = 0; r < CH; ++r) {
            const v2f xx = { xv[r], xv[r] };
            v2f g0 = {0.f, 0.f}, g1 = {0.f, 0.f}, g2 = {0.f, 0.f}, g3 = {0.f, 0.f};
            #pragma unroll
            for (int q = 0; q < HID / 2; q += 4) {   // 8 packed pairs
                v2f z0 = __builtin_elementwise_max(__builtin_elementwise_fma(xx, w1[q + 0], bb[q + 0]), (v2f)0.f);
                v2f z1 = __builtin_elementwise_max(__builtin_elementwise_fma(xx, w1[q + 1], bb[q + 1]), (v2f)0.f);
                v2f z2 = __builtin_elementwise_max(__builtin_elementwise_fma(xx, w1[q + 2], bb[q + 2]), (v2f)0.f);
                v2f z3 = __builtin_elementwise_max(__builtin_elementwise_fma(xx, w1[q + 3], bb[q + 3]), (v2f)0.f);
                g0 = __builtin_elementwise_fma(z0, w2[q + 0], g0);
                g1 = __builtin_elementwise_fma(z1, w2[q + 1], g1);
                g2 = __builtin_elementwise_fma(z2, w2[q + 2], g2);
                g3 = __builtin_elementwise_fma(z3, w2[q + 3], g3);
            }
            const v2f gs = (g0 + g1) + (g2 + g3);
            float pv = gs.x + gs.y;
            pv += __shfl_xor(pv, 1, 64);
            if ((tid & 1) == 0) part[(rbase + r) * CSTR + (tid >> 1)] = pv;
        }
    };

    float xa[CH], xb[CH];
    #pragma unroll
    for (int i = 0; i < CH; ++i) xa[i] = xp[(size_t)i * NF];

    #pragma unroll 1   // keep the body small so params stay register-resident
    for (int c = 0; c < NCH; c += 2) {
        #pragma unroll
        for (int i = 0; i < CH; ++i) xb[i] = xp[(size_t)((c + 1) * CH + i) * NF];
        compute8(xa, c * CH);
        if (c + 2 < NCH) {
            #pragma unroll
            for (int i = 0; i < CH; ++i) xa[i] = xp[(size_t)((c + 2) * CH + i) * NF];
        }
        compute8(xb, (c + 1) * CH);
    }
    __syncthreads();

    // ---- final reduce: 8 lanes per row, 16 strided reads each ----
    {
        const int row = tid >> 3;          // 0..31
        const int j   = tid & 7;           // 0..7
        float s = 0.f;
        #pragma unroll
        for (int i = 0; i < 16; ++i) s += part[row * CSTR + j + 8 * i];
        s += __shfl_xor(s, 1, 64);
        s += __shfl_xor(s, 2, 64);
        s += __shfl_xor(s, 4, 64);
        if (j == 0) atomicAdd(&out[row0 + row], s);  // 8 consecutive addrs/wave
    }
}

extern "C" void kernel_launch(void* const* d_in, const int* in_sizes, int n_in,
                              void* d_out, int out_size, void* d_ws, size_t ws_size,
                              hipStream_t stream) {
    const float* x    = (const float*)d_in[0];
    const float* W1   = (const float*)d_in[1];
    const float* b1   = (const float*)d_in[2];
    const float* W2   = (const float*)d_in[3];
    const float* b2   = (const float*)d_in[4];
    const float* bias = (const float*)d_in[5];
    float* out = (float*)d_out;

    nam_init<<<BATCH / BLOCK, BLOCK, 0, stream>>>(out, b2, bias);
    nam_main<<<RB * FG, BLOCK, 0, stream>>>(x, W1, b1, W2, out);
}